// Round 12
// baseline (41.558 us; speedup 1.0000x reference)
//
#include <hip/hip_runtime.h>

// LearnableDCT as GEMM on matrix cores — 32x32x16 bf16, NO LDS, NO barriers.
//
// Round-11 post-mortem: MfmaUtil 6% / VALUBusy 6% / occupancy 32% — 88% stall
// from the serial {load->MFMA->LDS->barrier->read->store->barrier} chain. The
// LDS epilogue existed only because 16x16 D-fragments store 64B chunks.
// 32x32x16's D layout (col=lane&31, row=(reg&3)+8*(reg>>2)+4*(lane>>5),
// m74/m101-verified) stores cols 0..31 of one k-row per reg = a full 128B
// line per half-wave. So: wave = 32 blocks x all 64 k, acc = 2x f32x16,
// 24 MFMA (hi/lo 3x: bh*xh + bh*xl + bl*xh), 32 full-line dword stores,
// zero synchronization, 12288 independent waves.

typedef float  f32x16 __attribute__((ext_vector_type(16)));
typedef __bf16 bf16x8 __attribute__((ext_vector_type(8)));

static __device__ __forceinline__ f32x16 mfma32(bf16x8 a, bf16x8 b, f32x16 c) {
    return __builtin_amdgcn_mfma_f32_32x32x16_bf16(a, b, c, 0, 0, 0);
}

// Pre-kernel: basis -> per-lane hi/lo A-fragments for 32x32x16.
// A mapping: lane l elem j -> row k = kt*32 + (l&31), col n = nc*16 + (l>>5)*8 + j.
// ws layout: [F=((kt*4+nc)*2+p)][lane][8 bf16] = 16 frags * 1KB = 16KB.
__global__ void basis_frags(const float* __restrict__ bsrc,
                            __bf16* __restrict__ ws)
{
    const int lane = threadIdx.x & 63;
    #pragma unroll
    for (int rr = 0; rr < 2; ++rr) {
        const int th = (threadIdx.x >> 6) + rr * 4;   // 0..7 : kt=th>>2, nc=th&3
        const int kk = ((th >> 2) << 5) + (lane & 31);
        const int nn = ((th & 3) << 4) + ((lane >> 5) << 3);
        const int Fh = th * 2, Fl = th * 2 + 1;
        #pragma unroll
        for (int j = 0; j < 8; ++j) {
            const float v = bsrc[kk * 64 + nn + j];
            const __bf16 h = (__bf16)v;
            ws[(Fh * 64 + lane) * 8 + j] = h;
            ws[(Fl * 64 + lane) * 8 + j] = (__bf16)(v - (float)h);
        }
    }
}

#define MAKE_BX(va, vb, XH, XL)                                        \
    {                                                                  \
        const float vv[8] = {va.x, va.y, va.z, va.w,                   \
                             vb.x, vb.y, vb.z, vb.w};                  \
        _Pragma("unroll")                                              \
        for (int j = 0; j < 8; ++j) {                                  \
            const __bf16 hh = (__bf16)vv[j];                           \
            XH[j] = hh;                                                \
            XL[j] = (__bf16)(vv[j] - (float)hh);                       \
        }                                                              \
    }

__global__ __launch_bounds__(256) void dct_mfma(
    const float* __restrict__ x,
    const __bf16* __restrict__ wsf,
    float* __restrict__ out)
{
    const int lane = threadIdx.x & 63;
    const int wv   = threadIdx.x >> 6;       // 0..3
    const int T    = blockIdx.x * 4 + wv;    // wave-tile id, 0..12287
    const int wb0  = (T & 1) << 5;           // 0 or 32
    const int hb   = (T >> 1) & 63;
    const int bc   = T >> 7;                 // 0..95
    const int c31  = lane & 31;              // block col within half-row
    const int half = lane >> 5;              // 0/1

    // A fragments (16KB ws, L1/L2-resident, shared by all waves)
    bf16x8 A[16];
    const uint4* wp = reinterpret_cast<const uint4*>(wsf) + lane;
    #pragma unroll
    for (int F = 0; F < 16; ++F)
        A[F] = __builtin_bit_cast(bf16x8, wp[F * 64]);

    // B: lane l supplies x row i = nc*2 + half of block wb0+c31 (8 floats)
    const float* xp = x + ((size_t)bc << 18) + ((size_t)hb << 12)
                        + ((wb0 + c31) << 3);

    f32x16 acc0 = {0.f}, acc1 = {0.f};
    #pragma unroll
    for (int nc = 0; nc < 4; ++nc) {
        const int i = nc * 2 + half;
        const float4 a = *reinterpret_cast<const float4*>(xp + i * 512);
        const float4 b = *reinterpret_cast<const float4*>(xp + i * 512 + 4);
        bf16x8 Xh, Xl;
        MAKE_BX(a, b, Xh, Xl)
        // interleave the two k-tiles for 2-way MFMA ILP
        acc0 = mfma32(A[(0 * 4 + nc) * 2 + 0], Xh, acc0);   // bh*xh (k 0..31)
        acc1 = mfma32(A[(1 * 4 + nc) * 2 + 0], Xh, acc1);   // bh*xh (k 32..63)
        acc0 = mfma32(A[(0 * 4 + nc) * 2 + 0], Xl, acc0);   // bh*xl
        acc1 = mfma32(A[(1 * 4 + nc) * 2 + 0], Xl, acc1);
        acc0 = mfma32(A[(0 * 4 + nc) * 2 + 1], Xh, acc0);   // bl*xh
        acc1 = mfma32(A[(1 * 4 + nc) * 2 + 1], Xh, acc1);
    }

    // D: reg r -> row (r&3)+8*(r>>2)+4*half, col c31. Lanes 0-31 cover
    // cols wb0..wb0+31 contiguously = one full 128B line per half-wave.
    float* ob = out + ((size_t)bc << 18) + (hb << 6) + wb0 + c31;
    #pragma unroll
    for (int r = 0; r < 16; ++r) {
        const int row = (r & 3) + ((r >> 2) << 3) + (half << 2);
        __builtin_nontemporal_store(acc0[r], ob + ((size_t)row << 12));
        __builtin_nontemporal_store(acc1[r], ob + ((size_t)(row + 32) << 12));
    }
}

extern "C" void kernel_launch(void* const* d_in, const int* in_sizes, int n_in,
                              void* d_out, int out_size, void* d_ws, size_t ws_size,
                              hipStream_t stream) {
    const float* x     = (const float*)d_in[0];
    const float* basis = (const float*)d_in[1];
    float* out         = (float*)d_out;
    __bf16* ws         = (__bf16*)d_ws;    // 16 KB

    basis_frags<<<dim3(1), dim3(256), 0, stream>>>(basis, ws);
    // 12288 wave-tiles / 4 per WG = 3072 WGs
    dct_mfma<<<dim3(3072), dim3(256), 0, stream>>>(x, ws, out);
}

// Round 13
// 41.194 us; speedup vs baseline: 1.0088x; 1.0088x over previous
//
#include <hip/hip_runtime.h>

// LearnableDCT as GEMM on matrix cores — 32x32x16 bf16, A-operands fed from LDS.
//
// Round-12 post-mortem: VGPR=52 proves A[16] (64 regs) was demoted yet again —
// every MFMA re-loads its A operand from global on the vmcnt queue, serialized
// against x-loads and the 32 output stores (~200cy each, ~20K cy/wave). The
// fill kernel hits 7 TB/s at 9% occupancy, so the store path is fine; the
// A-reload chain is the stall. Fix: A-table (16KB) lives in LDS (staged once
// per WG, single barrier). MFMA A-operands come via ds_read_b128 at lane*16 —
// contiguous, conflict-free, on the lgkmcnt queue (no vmcnt contention),
// fine-grained-interleaved with MFMA by the compiler. Register demand is
// acc(32)+X(8)+addr by design — nothing for regalloc to demote.

typedef float  f32x16 __attribute__((ext_vector_type(16)));
typedef __bf16 bf16x8 __attribute__((ext_vector_type(8)));

static __device__ __forceinline__ f32x16 mfma32(bf16x8 a, bf16x8 b, f32x16 c) {
    return __builtin_amdgcn_mfma_f32_32x32x16_bf16(a, b, c, 0, 0, 0);
}

// Pre-kernel: basis -> per-lane hi/lo A-fragments for 32x32x16 (round-12
// verified). A mapping: lane l elem j -> row k = kt*32+(l&31),
// col n = nc*16 + (l>>5)*8 + j. ws: [F=((kt*4+nc)*2+p)][lane][8bf16] = 16KB.
__global__ void basis_frags(const float* __restrict__ bsrc,
                            __bf16* __restrict__ ws)
{
    const int lane = threadIdx.x & 63;
    #pragma unroll
    for (int rr = 0; rr < 2; ++rr) {
        const int th = (threadIdx.x >> 6) + rr * 4;   // 0..7 : kt=th>>2, nc=th&3
        const int kk = ((th >> 2) << 5) + (lane & 31);
        const int nn = ((th & 3) << 4) + ((lane >> 5) << 3);
        const int Fh = th * 2, Fl = th * 2 + 1;
        #pragma unroll
        for (int j = 0; j < 8; ++j) {
            const float v = bsrc[kk * 64 + nn + j];
            const __bf16 h = (__bf16)v;
            ws[(Fh * 64 + lane) * 8 + j] = h;
            ws[(Fl * 64 + lane) * 8 + j] = (__bf16)(v - (float)h);
        }
    }
}

#define MAKE_BX(va, vb, XH, XL)                                        \
    {                                                                  \
        const float vv[8] = {va.x, va.y, va.z, va.w,                   \
                             vb.x, vb.y, vb.z, vb.w};                  \
        _Pragma("unroll")                                              \
        for (int j = 0; j < 8; ++j) {                                  \
            const __bf16 hh = (__bf16)vv[j];                           \
            XH[j] = hh;                                                \
            XL[j] = (__bf16)(vv[j] - (float)hh);                       \
        }                                                              \
    }

__global__ __launch_bounds__(256) void dct_mfma(
    const float* __restrict__ x,
    const __bf16* __restrict__ wsf,
    float* __restrict__ out)
{
    __shared__ uint4 Alds[16 * 64];   // [F][lane], 16 KB

    const int tid  = threadIdx.x;
    const int lane = tid & 63;
    const int wv   = tid >> 6;              // 0..3
    const int T    = blockIdx.x * 4 + wv;   // wave-tile id, 0..12287
    const int wb0  = (T & 1) << 5;          // 0 or 32
    const int hb   = (T >> 1) & 63;
    const int bc   = T >> 7;                // 0..95
    const int c31  = lane & 31;
    const int half = lane >> 5;             // 0/1

    // Stage A-table into LDS: 1024 uint4, 4 per thread.
    {
        const uint4* ws4 = reinterpret_cast<const uint4*>(wsf);
        #pragma unroll
        for (int r = 0; r < 4; ++r)
            Alds[tid + r * 256] = ws4[tid + r * 256];
    }
    __syncthreads();

    // B: lane l supplies x row i = nc*2 + half of block wb0+c31 (8 floats)
    const float* xp = x + ((size_t)bc << 18) + ((size_t)hb << 12)
                        + ((wb0 + c31) << 3);

#define ALD(F) __builtin_bit_cast(bf16x8, Alds[((F) << 6) + lane])

    f32x16 acc0 = {0.f}, acc1 = {0.f};
    #pragma unroll
    for (int nc = 0; nc < 4; ++nc) {
        const int i = nc * 2 + half;
        const float4 a = *reinterpret_cast<const float4*>(xp + i * 512);
        const float4 b = *reinterpret_cast<const float4*>(xp + i * 512 + 4);
        bf16x8 Xh, Xl;
        MAKE_BX(a, b, Xh, Xl)
        acc0 = mfma32(ALD((0 * 4 + nc) * 2 + 0), Xh, acc0);   // bh*xh (k 0..31)
        acc1 = mfma32(ALD((1 * 4 + nc) * 2 + 0), Xh, acc1);   // bh*xh (k 32..63)
        acc0 = mfma32(ALD((0 * 4 + nc) * 2 + 0), Xl, acc0);   // bh*xl
        acc1 = mfma32(ALD((1 * 4 + nc) * 2 + 0), Xl, acc1);
        acc0 = mfma32(ALD((0 * 4 + nc) * 2 + 1), Xh, acc0);   // bl*xh
        acc1 = mfma32(ALD((1 * 4 + nc) * 2 + 1), Xh, acc1);
    }

    // D: reg r -> row (r&3)+8*(r>>2)+4*half, col c31 (m74/m101-verified).
    // Lanes 0..31 cover cols wb0..wb0+31 = full 128B line per half-wave.
    float* ob = out + ((size_t)bc << 18) + (hb << 6) + wb0 + c31;
    #pragma unroll
    for (int r = 0; r < 16; ++r) {
        const int row = (r & 3) + ((r >> 2) << 3) + (half << 2);
        __builtin_nontemporal_store(acc0[r], ob + ((size_t)row << 12));
        __builtin_nontemporal_store(acc1[r], ob + ((size_t)(row + 32) << 12));
    }
}

extern "C" void kernel_launch(void* const* d_in, const int* in_sizes, int n_in,
                              void* d_out, int out_size, void* d_ws, size_t ws_size,
                              hipStream_t stream) {
    const float* x     = (const float*)d_in[0];
    const float* basis = (const float*)d_in[1];
    float* out         = (float*)d_out;
    __bf16* ws         = (__bf16*)d_ws;    // 16 KB

    basis_frags<<<dim3(1), dim3(256), 0, stream>>>(basis, ws);
    // 12288 wave-tiles / 4 per WG = 3072 WGs
    dct_mfma<<<dim3(3072), dim3(256), 0, stream>>>(x, ws, out);
}

// Round 14
// 36.989 us; speedup vs baseline: 1.1235x; 1.1137x over previous
//
#include <hip/hip_runtime.h>

// LearnableDCT as GEMM on matrix cores — 32x32x16 bf16, single fused kernel.
//
// Round-13 post-mortem: four different structures all converge on ~41us.
// Steady state = 98MB HBM writes + 98MB L3-hit reads = 196MB combined;
// copy ceiling 6.29 TB/s -> 31us floor. We're at 76% of that. Remaining
// overhead: the serialized basis_frags pre-kernel launch (~3-6us in the
// graph) and per-wave startup latency. Round 14: (1) fuse fragment prep
// into the main kernel (per-WG hi/lo conversion of the 16KB basis into
// LDS — basis is L2-resident after the first WG); (2) prefetch the 8 x
// float4 loads BEFORE staging so HBM/L3 read latency hides under the
// conversion + barrier. Datapath & store layout unchanged (m74/m101 D).

typedef float  f32x16 __attribute__((ext_vector_type(16)));
typedef __bf16 bf16x8 __attribute__((ext_vector_type(8)));

static __device__ __forceinline__ f32x16 mfma32(bf16x8 a, bf16x8 b, f32x16 c) {
    return __builtin_amdgcn_mfma_f32_32x32x16_bf16(a, b, c, 0, 0, 0);
}

#define MAKE_BX(va, vb, XH, XL)                                        \
    {                                                                  \
        const float vv[8] = {va.x, va.y, va.z, va.w,                   \
                             vb.x, vb.y, vb.z, vb.w};                  \
        _Pragma("unroll")                                              \
        for (int j = 0; j < 8; ++j) {                                  \
            const __bf16 hh = (__bf16)vv[j];                           \
            XH[j] = hh;                                                \
            XL[j] = (__bf16)(vv[j] - (float)hh);                       \
        }                                                              \
    }

__global__ __launch_bounds__(256) void dct_mfma(
    const float* __restrict__ x,
    const float* __restrict__ basis,
    float* __restrict__ out)
{
    __shared__ bf16x8 Alds[16 * 64];   // [F][lane], 16 KB

    const int tid  = threadIdx.x;
    const int lane = tid & 63;
    const int wv   = tid >> 6;              // 0..3
    const int T    = blockIdx.x * 4 + wv;   // wave-tile id, 0..12287
    const int wb0  = (T & 1) << 5;          // 0 or 32
    const int hb   = (T >> 1) & 63;
    const int bc   = T >> 7;                // 0..95
    const int c31  = lane & 31;
    const int half = lane >> 5;             // 0/1

    // ---- prefetch B: 8 x float4 (rows i = nc*2+half of block wb0+c31) ----
    // Issued first so the global-read latency hides under fragment staging.
    const float* xp = x + ((size_t)bc << 18) + ((size_t)hb << 12)
                        + ((wb0 + c31) << 3);
    float4 xa[4], xb[4];
    #pragma unroll
    for (int nc = 0; nc < 4; ++nc) {
        const int i = nc * 2 + half;
        xa[nc] = *reinterpret_cast<const float4*>(xp + i * 512);
        xb[nc] = *reinterpret_cast<const float4*>(xp + i * 512 + 4);
    }

    // ---- stage hi/lo A-fragments into LDS (was the basis_frags kernel) ----
    // Fragment F = ((kt*4+nc)*2+p): lane l elem j holds
    // basis[kt*32+(l&31)][nc*16+(l>>5)*8+j], p=0 -> hi bf16, p=1 -> lo.
    #pragma unroll
    for (int r = 0; r < 4; ++r) {
        const int s  = tid + (r << 8);         // 0..1023
        const int F  = s >> 6;                 // wave-uniform
        const int ln = s & 63;
        const int k  = ((F >> 3) << 5) + (ln & 31);
        const int n  = (((F >> 1) & 3) << 4) + ((ln >> 5) << 3);
        const float4 v0 = *reinterpret_cast<const float4*>(basis + k * 64 + n);
        const float4 v1 = *reinterpret_cast<const float4*>(basis + k * 64 + n + 4);
        const float vv[8] = {v0.x, v0.y, v0.z, v0.w, v1.x, v1.y, v1.z, v1.w};
        bf16x8 f;
        if (F & 1) {                           // lo part
            #pragma unroll
            for (int j = 0; j < 8; ++j) {
                const __bf16 h = (__bf16)vv[j];
                f[j] = (__bf16)(vv[j] - (float)h);
            }
        } else {                               // hi part
            #pragma unroll
            for (int j = 0; j < 8; ++j)
                f[j] = (__bf16)vv[j];
        }
        Alds[s] = f;
    }
    __syncthreads();

#define ALD(F) Alds[((F) << 6) + lane]

    f32x16 acc0 = {0.f}, acc1 = {0.f};
    #pragma unroll
    for (int nc = 0; nc < 4; ++nc) {
        bf16x8 Xh, Xl;
        MAKE_BX(xa[nc], xb[nc], Xh, Xl)
        acc0 = mfma32(ALD((0 * 4 + nc) * 2 + 0), Xh, acc0);   // bh*xh (k 0..31)
        acc1 = mfma32(ALD((1 * 4 + nc) * 2 + 0), Xh, acc1);   // bh*xh (k 32..63)
        acc0 = mfma32(ALD((0 * 4 + nc) * 2 + 0), Xl, acc0);   // bh*xl
        acc1 = mfma32(ALD((1 * 4 + nc) * 2 + 0), Xl, acc1);
        acc0 = mfma32(ALD((0 * 4 + nc) * 2 + 1), Xh, acc0);   // bl*xh
        acc1 = mfma32(ALD((1 * 4 + nc) * 2 + 1), Xh, acc1);
    }

    // D: reg r -> row (r&3)+8*(r>>2)+4*half, col c31 (m74/m101-verified).
    // Lanes 0..31 cover cols wb0..wb0+31 = full 128B line per half-wave.
    float* ob = out + ((size_t)bc << 18) + (hb << 6) + wb0 + c31;
    #pragma unroll
    for (int r = 0; r < 16; ++r) {
        const int row = (r & 3) + ((r >> 2) << 3) + (half << 2);
        __builtin_nontemporal_store(acc0[r], ob + ((size_t)row << 12));
        __builtin_nontemporal_store(acc1[r], ob + ((size_t)(row + 32) << 12));
    }
}

extern "C" void kernel_launch(void* const* d_in, const int* in_sizes, int n_in,
                              void* d_out, int out_size, void* d_ws, size_t ws_size,
                              hipStream_t stream) {
    const float* x     = (const float*)d_in[0];
    const float* basis = (const float*)d_in[1];
    float* out         = (float*)d_out;

    // 12288 wave-tiles / 4 per WG = 3072 WGs, single fused kernel
    dct_mfma<<<dim3(3072), dim3(256), 0, stream>>>(x, basis, out);
}